// Round 15
// baseline (347.988 us; speedup 1.0000x reference)
//
#include <hip/hip_runtime.h>
#include <math.h>

#define HH_ 96
#define WW_ 160
#define HW 15360          // 96*160
#define NPIX 61440        // 4*HW
#define CC 256
#define C0 320            // padded conv0 Cin
#define FF 64
#define H2 192
#define W2 320
#define OHW 61440         // 192*320
#define HO 768
#define WO 1280

typedef __attribute__((ext_vector_type(8))) short short8;
typedef __attribute__((ext_vector_type(4))) float f32x4;

__device__ __forceinline__ float bf2f(ushort u) {
    union { unsigned int i; float f; } v; v.i = ((unsigned int)u) << 16; return v.f;
}
__device__ __forceinline__ ushort f2bf(float f) {
    union { float f; unsigned int i; } v; v.f = f;
    unsigned int u = v.i;
    return (ushort)((u + 0x7FFFu + ((u >> 16) & 1u)) >> 16);
}

// ---------------- fused stats + pack (raw bf16) + LN ------------------------
__global__ __launch_bounds__(256) void normpack_kernel(
    const float* __restrict__ x1, const float* __restrict__ x2, const float* __restrict__ xt,
    const float* __restrict__ gam, const float* __restrict__ bet,
    ushort* __restrict__ x1c, ushort* __restrict__ x2c,
    ushort* __restrict__ Xhi, float* __restrict__ inv1, float* __restrict__ inv2) {
    __shared__ ushort tile[32 * 258];
    __shared__ float sred[4][32][2];
    const int t = threadIdx.x;
    const int w = t >> 6, l = t & 63;
    const int px4 = l & 7;
    const int cbase = t >> 3;
    const int pxt = blockIdx.x, which = blockIdx.y, b = blockIdx.z;
    const float* src = (which == 0 ? x1 : which == 1 ? x2 : xt);
    src += (size_t)b * CC * HW + pxt * 32;

    float s1[4] = {0.f, 0.f, 0.f, 0.f}, s2[4] = {0.f, 0.f, 0.f, 0.f};
#pragma unroll
    for (int it = 0; it < 8; ++it) {
        int c = it * 32 + cbase;
        f32x4 v4 = *(const f32x4*)(src + (size_t)c * HW + px4 * 4);
#pragma unroll
        for (int j = 0; j < 4; ++j) {
            float f = v4[j];
            s1[j] += f; s2[j] += f * f;
            tile[(px4 * 4 + j) * 258 + c] = f2bf(f);
        }
    }
#pragma unroll
    for (int j = 0; j < 4; ++j) {
        s1[j] += __shfl_xor(s1[j], 8);  s1[j] += __shfl_xor(s1[j], 16); s1[j] += __shfl_xor(s1[j], 32);
        s2[j] += __shfl_xor(s2[j], 8);  s2[j] += __shfl_xor(s2[j], 16); s2[j] += __shfl_xor(s2[j], 32);
    }
    if ((l >> 3) == 0) {
#pragma unroll
        for (int j = 0; j < 4; ++j) {
            sred[w][px4 * 4 + j][0] = s1[j];
            sred[w][px4 * 4 + j][1] = s2[j];
        }
    }
    __syncthreads();

    const int px = t >> 3, grp = t & 7;
    float S1 = sred[0][px][0] + sred[1][px][0] + sred[2][px][0] + sred[3][px][0];
    float S2 = sred[0][px][1] + sred[1][px][1] + sred[2][px][1] + sred[3][px][1];
    const int p = b * HW + pxt * 32 + px;
    const ushort* row = &tile[px * 258];
    if (which < 2) {
        float inv = 1.f / fmaxf(sqrtf(S2), 1e-12f);
        if (grp == 0) (which == 0 ? inv1 : inv2)[p] = inv;
        ushort* dst = (which == 0 ? x1c : x2c) + (size_t)p * CC + grp * 32;
#pragma unroll
        for (int k = 0; k < 4; ++k) {
            short8 o;
#pragma unroll
            for (int h = 0; h < 4; ++h) {
                unsigned int u2 = *(const unsigned int*)(row + grp * 32 + k * 8 + h * 2);
                o[h * 2]     = (short)(u2 & 0xFFFF);
                o[h * 2 + 1] = (short)(u2 >> 16);
            }
            *(short8*)(dst + k * 8) = o;
        }
    } else {
        float m = S1 * (1.f / 256.f);
        float var = fmaxf(S2 * (1.f / 256.f) - m * m, 0.f);
        float rs = rsqrtf(var + 1e-5f);
        ushort* dst = Xhi + (size_t)p * C0 + grp * 32;
#pragma unroll
        for (int k = 0; k < 4; ++k) {
            short8 o;
#pragma unroll
            for (int h = 0; h < 4; ++h) {
                unsigned int u2 = *(const unsigned int*)(row + grp * 32 + k * 8 + h * 2);
                int c = grp * 32 + k * 8 + h * 2;
                float f0 = (bf2f((ushort)(u2 & 0xFFFF)) - m) * rs * gam[c] + bet[c];
                float f1 = (bf2f((ushort)(u2 >> 16)) - m) * rs * gam[c + 1] + bet[c + 1];
                o[h * 2]     = (short)f2bf(f0);
                o[h * 2 + 1] = (short)f2bf(f1);
            }
            *(short8*)(dst + k * 8) = o;
        }
        if (grp < 4) {
            short8 z = {0, 0, 0, 0, 0, 0, 0, 0};
            *(short8*)(Xhi + (size_t)p * C0 + 256 + grp * 16) = z;
            *(short8*)(Xhi + (size_t)p * C0 + 256 + grp * 16 + 8) = z;
        }
    }
}

// ---------------------------------------------------------------- corr ------
// round-13 form: 960 blocks, full dy loop per wave.
__global__ __launch_bounds__(256) void corr_mfma_kernel(
    const ushort* __restrict__ x1c, const ushort* __restrict__ x2c,
    const float* __restrict__ inv1, const float* __restrict__ inv2,
    ushort* __restrict__ Xhi) {
    const int lane = threadIdx.x & 63;
    const int wv = threadIdx.x >> 6;
    const int sid = ((blockIdx.x & 7) * 120) + (blockIdx.x >> 3);   // 960 blocks
    const int b  = sid / 240;
    const int rem = sid % 240;
    const int uq = rem / 10, xt = rem % 10;
    const int u = uq * 4 + wv;
    const int x0 = xt * 16;
    const int jl = lane & 15;
    const int kg = lane >> 4;
    const short8 zero8 = {0, 0, 0, 0, 0, 0, 0, 0};

    short8 qf[8];
    {
        size_t qb = ((size_t)b * HW + u * WW_ + x0 + jl) * CC + kg * 8;
#pragma unroll
        for (int ks = 0; ks < 8; ++ks)
            qf[ks] = *(const short8*)(x1c + qb + ks * 32);
    }
    float iv1v[4];
#pragma unroll
    for (int r = 0; r < 4; ++r)
        iv1v[r] = inv1[b * HW + u * WW_ + x0 + kg * 4 + r];

    for (int dy = -3; dy <= 3; ++dy) {
        const int y = u + dy;
        if ((unsigned)y >= (unsigned)HH_) continue;
        const int w = u + 2 * dy;
        const bool rowok = (unsigned)w < (unsigned)HH_;

        f32x4 acc0 = (f32x4){0.f, 0.f, 0.f, 0.f};
        f32x4 acc1 = (f32x4){0.f, 0.f, 0.f, 0.f};
        if (rowok) {
#pragma unroll
            for (int nt = 0; nt < 2; ++nt) {
                int kx = x0 - 6 + jl + 16 * nt;
                bool ok = (unsigned)kx < (unsigned)WW_;
                int kxc = min(max(kx, 0), WW_ - 1);
                size_t kb = ((size_t)b * HW + w * WW_ + kxc) * CC + kg * 8;
#pragma unroll
                for (int ks = 0; ks < 8; ++ks) {
                    short8 bv = *(const short8*)(x2c + kb + ks * 32);
                    if (!ok) bv = zero8;
                    if (nt == 0)
                        acc0 = __builtin_amdgcn_mfma_f32_16x16x32_bf16(qf[ks], bv, acc0, 0, 0, 0);
                    else
                        acc1 = __builtin_amdgcn_mfma_f32_16x16x32_bf16(qf[ks], bv, acc1, 0, 0, 0);
                }
            }
        }
#pragma unroll
        for (int nt = 0; nt < 2; ++nt) {
            int j = jl + 16 * nt;
#pragma unroll
            for (int r = 0; r < 4; ++r) {
                int q = kg * 4 + r;
                int tt = j - q - 6;
                if (tt & 1) continue;
                int dx = tt >> 1;
                if (dx < -3 || dx > 3) continue;
                int cx = x0 + q + dx;
                if ((unsigned)cx >= (unsigned)WW_) continue;
                float v = 0.f;
                if (rowok) {
                    int pbx = min(max(x0 + q + 2 * dx, 0), WW_ - 1);
                    float iv2 = inv2[b * HW + w * WW_ + pbx];
                    v = (nt == 0 ? acc0[r] : acc1[r]) * iv1v[r] * iv2;
                }
                size_t o = ((size_t)(b * HW + y * WW_ + cx)) * C0
                         + 256 + (dy + 3) * 7 + (dx + 3);
                Xhi[o] = f2bf(v);
            }
        }
    }
}

// ------------------------------------------------------------ weight pack ---
__global__ void pack_w_all(const float* __restrict__ w0, const float* __restrict__ wr1,
                           const float* __restrict__ wr2, const float* __restrict__ w2,
                           const float* __restrict__ w3, const float* __restrict__ wdec,
                           ushort* __restrict__ W0, ushort* __restrict__ WR1,
                           ushort* __restrict__ WR2, ushort* __restrict__ W2o,
                           ushort* __restrict__ W3o, ushort* __restrict__ WD) {
    int job = blockIdx.y;
    const float* w = job == 0 ? w0 : job == 1 ? wr1 : job == 2 ? wr2
                   : job == 3 ? w2 : job == 4 ? w3 : wdec;
    ushort* dst = job == 0 ? W0 : job == 1 ? WR1 : job == 2 ? WR2
                : job == 3 ? W2o : job == 4 ? W3o : WD;
    int CinReal = job == 0 ? 305 : 64;
    int KC = job == 0 ? 10 : 2;
    int isDeconv = (job == 5);
    int gid = blockIdx.x * blockDim.x + threadIdx.x;
    int total = 9 * KC * 4 * 64;
    if (gid >= total) return;
    int lane = gid & 63;
    int nt = (gid >> 6) & 3;
    int kc = (gid >> 8) % KC;
    int slot = (gid >> 8) / KC;
    int co = nt * 16 + (lane & 15);
    int ky = slot / 3, kx = slot % 3;
    for (int j = 0; j < 8; ++j) {
        int ci = kc * 32 + (lane >> 4) * 8 + j;
        float v = 0.f;
        if (ci < CinReal) {
            if (isDeconv) v = w[((size_t)(ci * 64 + co) * 3 + (2 - ky)) * 3 + (2 - kx)];
            else          v = w[((size_t)(co * CinReal + ci) * 3 + ky) * 3 + kx];
        }
        dst[(size_t)gid * 8 + j] = f2bf(v);
    }
}

// --- unified conv core: 2 rows x 16 px tile, wave = (row, co-half), dbuf ----
// grid 1920 -> 7.5 waves/SIMD. LDS chunk: kg[4] x row[4] x px[18] x ch[8],
// kg stride 584 (pad +8), dbuf offset 2336. Template over KC (CIN = 32*KC).
template<int KC>
__global__ __launch_bounds__(256, 8) void conv_ldsK(
    const ushort* __restrict__ Ahi,
    const ushort* __restrict__ Whi,
    const float* __restrict__ bias,
    ushort* __restrict__ Ohi,
    const ushort* __restrict__ Rhi,
    float slope, int act, int hasres) {
    constexpr int CIN = KC * 32;
    __shared__ ushort lds[2 * 2336];
    const int t = threadIdx.x;
    const int lane = t & 63;
    const int wave = t >> 6;
    const int row_w = wave >> 1;
    const int coh = wave & 1;
    const int kg = lane >> 4;
    const int jl = lane & 15;
    const short8 zero8 = {0, 0, 0, 0, 0, 0, 0, 0};

    const int sid = ((blockIdx.x & 7) * 240) + (blockIdx.x >> 3);   // 1920 blocks
    const int b0 = sid / 480;
    const int rm = sid % 480;
    const int yp = rm / 10, xw = rm % 10;
    const int y0 = yp * 2;
    const int x0 = xw * 16;
    const size_t rowbase = (size_t)b0 * HW;

    f32x4 acc[2];
    acc[0] = (f32x4){0.f, 0.f, 0.f, 0.f};
    acc[1] = (f32x4){0.f, 0.f, 0.f, 0.f};

    auto stage = [&](ushort* buf, int kc) {
#pragma unroll
        for (int i = 0; i < 2; ++i) {
            int e = t + i * 256;
            if (e < 288) {
                int kge = e & 3;
                int q = e >> 2;
                int pe = q % 18;
                int re = q / 18;
                int gy = y0 - 1 + re, gx = x0 - 1 + pe;
                bool ok = ((unsigned)gy < 96u) && ((unsigned)gx < 160u);
                short8 vh = zero8;
                if (ok) {
                    size_t ga = ((rowbase + gy * WW_ + gx) * (size_t)CIN) + kc * 32 + kge * 8;
                    vh = *(const short8*)(Ahi + ga);
                }
                *(short8*)(buf + kge * 584 + (re * 18 + pe) * 8) = vh;
            }
        }
    };

    stage(lds, 0);

#pragma unroll 1
    for (int kc = 0; kc < KC; ++kc) {
        __syncthreads();
        if (kc + 1 < KC) stage(lds + ((kc + 1) & 1) * 2336, kc + 1);
        const ushort* bufc = lds + (kc & 1) * 2336;
#pragma unroll
        for (int tap = 0; tap < 9; ++tap) {
            const int dy = tap / 3 - 1, dx = tap % 3 - 1;
            const int abase = kg * 584 + (row_w + dy + 1) * 144 + (jl + dx + 1) * 8;
            short8 ah = *(const short8*)(bufc + abase);
            const ushort* wt = Whi + (size_t)(tap * KC + kc) * 2048;
#pragma unroll
            for (int nt = 0; nt < 2; ++nt) {
                short8 bh = *(const short8*)(wt + (((coh << 1) | nt) * 64 + lane) * 8);
                acc[nt] = __builtin_amdgcn_mfma_f32_16x16x32_bf16(ah, bh, acc[nt], 0, 0, 0);
            }
        }
    }

#pragma unroll
    for (int r = 0; r < 4; ++r) {
        size_t pr = rowbase + (y0 + row_w) * WW_ + x0 + kg * 4 + r;
#pragma unroll
        for (int nt = 0; nt < 2; ++nt) {
            int co = ((coh << 1) | nt) * 16 + jl;
            float vv = acc[nt][r] + bias[co];
            size_t oo = pr * 64 + co;
            if (hasres) vv += bf2f(Rhi[oo]);
            if (act) vv = vv >= 0.f ? vv : vv * slope;
            Ohi[oo] = f2bf(vv);
        }
    }
}

// -------- fused transposed conv (4 par), bf16 out, wave = (row, co-half) ----
__global__ __launch_bounds__(256, 6) void deconv_fused_kernel(
    const ushort* __restrict__ Ahi,
    const ushort* __restrict__ Whi,
    const float* __restrict__ bias,
    ushort* __restrict__ decb) {
    const int lane = threadIdx.x & 63;
    const int wave = threadIdx.x >> 6;
    const int row_w = wave >> 1;
    const int coh = wave & 1;
    const int kg = lane >> 4;
    const short8 zero8 = {0, 0, 0, 0, 0, 0, 0, 0};

    const int sid = ((blockIdx.x & 7) * 240) + (blockIdx.x >> 3);   // 1920 blocks
    const int b0 = sid / 480;
    const int rm = sid % 480;
    const int yp = rm / 10, xh = rm % 10;
    const int y0 = yp * 2 + row_w;
    const int x0 = xh * 16;
    const size_t rowbase = (size_t)b0 * HW;

    f32x4 acc[4][2];
#pragma unroll
    for (int p = 0; p < 4; ++p) {
        acc[p][0] = (f32x4){0.f, 0.f, 0.f, 0.f};
        acc[p][1] = (f32x4){0.f, 0.f, 0.f, 0.f};
    }

    const int nuse[4]   = {4, 2, 2, 1};
    const int upar[4][4] = {{0, 1, 2, 3}, {1, 3, -1, -1}, {2, 3, -1, -1}, {3, -1, -1, -1}};
    const int uslt[4][4] = {{4, 3, 1, 0}, {5, 2, -1, -1}, {7, 6, -1, -1}, {8, -1, -1, -1}};

#pragma unroll
    for (int o = 0; o < 4; ++o) {
        const int ody = o >> 1, odx = o & 1;
        int yy = y0 + ody, xx = x0 + (lane & 15) + odx;
        bool v = (unsigned)yy < 96u && (unsigned)xx < 160u;
        int yyc = min(yy, 95), xxc = min(xx, 159);
        size_t a = (rowbase + yyc * WW_ + xxc) * 64 + kg * 8;
#pragma unroll
        for (int kc = 0; kc < 2; ++kc) {
            short8 ah = *(const short8*)(Ahi + a + kc * 32);
            if (!v) ah = zero8;
#pragma unroll
            for (int u = 0; u < 4; ++u) {
                if (u >= nuse[o]) break;
                int par = upar[o][u], slot = uslt[o][u];
#pragma unroll
                for (int nt = 0; nt < 2; ++nt) {
                    short8 bh = *(const short8*)(Whi + ((size_t)slot * 2 + kc) * 2048
                                                 + (((coh << 1) | nt) * 64 + lane) * 8);
                    acc[par][nt] = __builtin_amdgcn_mfma_f32_16x16x32_bf16(ah, bh, acc[par][nt], 0, 0, 0);
                }
            }
        }
    }

#pragma unroll
    for (int r = 0; r < 4; ++r) {
        int x2 = x0 + kg * 4 + r;
#pragma unroll
        for (int par = 0; par < 4; ++par) {
            int py = par >> 1, px = par & 1;
            size_t po = ((size_t)b0 * H2 + 2 * y0 + py) * W2 + 2 * x2 + px;
#pragma unroll
            for (int nt = 0; nt < 2; ++nt) {
                int co = ((coh << 1) | nt) * 16 + (lane & 15);
                decb[po * 64 + co] = f2bf(acc[par][nt][r] + bias[co]);
            }
        }
    }
}

// ------------------------- flow: 2 threads per px (32 ch each) --------------
__global__ __launch_bounds__(256) void flow_kernel(const ushort* __restrict__ decb,
                                                   const float* __restrict__ wf,
                                                   const float* __restrict__ bf2v,
                                                   float* __restrict__ flow) {
    __shared__ float wsm[1152];
    for (int i = threadIdx.x; i < 1152; i += 256) wsm[i] = wf[i];
    __syncthreads();
    int fid = ((blockIdx.x & 7) * 240) + (blockIdx.x >> 3);   // 1920 blocks
    int tid = fid * 256 + threadIdx.x;
    int p = tid >> 1, half = tid & 1;
    if (p >= 4 * OHW) return;
    int b = p / OHW, rem = p % OHW, oy = rem / W2, ox = rem % W2;
    float a0 = 0.f, a1 = 0.f;
    for (int ky = 0; ky < 3; ++ky) {
        int yy = oy + ky - 1;
        if ((unsigned)yy >= (unsigned)H2) continue;
        for (int kx = 0; kx < 3; ++kx) {
            int xx = ox + kx - 1;
            if ((unsigned)xx >= (unsigned)W2) continue;
            size_t base = ((size_t)b * OHW + yy * W2 + xx) * 64;
            int tap = ky * 3 + kx;
#pragma unroll
            for (int c8 = 0; c8 < 4; ++c8) {
                int cg = half * 4 + c8;
                short8 v8 = *(const short8*)(decb + base + cg * 8);
#pragma unroll
                for (int j = 0; j < 8; ++j) {
                    float f = bf2f((ushort)v8[j]);
                    int ci = cg * 8 + j;
                    a0 += f * wsm[ci * 9 + tap];
                    a1 += f * wsm[(64 + ci) * 9 + tap];
                }
            }
        }
    }
    a0 += __shfl_xor(a0, 1);
    a1 += __shfl_xor(a1, 1);
    if (half == 0) {
        flow[(size_t)(b * 2 + 0) * OHW + rem] = a0 + bf2v[0];
        flow[(size_t)(b * 2 + 1) * OHW + rem] = a1 + bf2v[1];
    }
}

// --------------------------------------------- resize: float4-wide outputs --
__global__ __launch_bounds__(256) void resize_kernel(const float* __restrict__ flow,
                                                     float* __restrict__ out) {
    int idx = blockIdx.x * blockDim.x + threadIdx.x;
    int total = 4 * 2 * HO * (WO / 4);
    if (idx >= total) return;
    int qx = idx % (WO / 4);
    int oy = (idx / (WO / 4)) % HO;
    int c  = (idx / ((WO / 4) * HO)) % 2;
    int b  = idx / ((WO / 4) * HO * 2);

    float sy = (oy + 0.5f) * 0.25f - 0.5f;
    int y0 = (int)floorf(sy);
    float fy = sy - y0;
    int y0c = min(max(y0, 0), H2 - 1);
    int y1c = min(max(y0 + 1, 0), H2 - 1);
    const float* r0 = flow + ((size_t)(b * 2 + c) * H2 + y0c) * W2;
    const float* r1 = flow + ((size_t)(b * 2 + c) * H2 + y1c) * W2;
    int xm = max(qx - 1, 0), xp = min(qx + 1, W2 - 1);
    float fm = (1.f - fy) * r0[xm] + fy * r1[xm];
    float f0 = (1.f - fy) * r0[qx] + fy * r1[qx];
    float fp = (1.f - fy) * r0[xp] + fy * r1[xp];
    f32x4 o;
    o[0] = (0.375f * fm + 0.625f * f0) * 4.0f;
    o[1] = (0.125f * fm + 0.875f * f0) * 4.0f;
    o[2] = (0.875f * f0 + 0.125f * fp) * 4.0f;
    o[3] = (0.625f * f0 + 0.375f * fp) * 4.0f;
    *(f32x4*)(out + (((size_t)(b * 2 + c) * HO + oy) * WO) + qx * 4) = o;
}

// =================================================================== host ===
extern "C" void kernel_launch(void* const* d_in, const int* in_sizes, int n_in,
                              void* d_out, int out_size, void* d_ws, size_t ws_size,
                              hipStream_t stream) {
    const float* x1   = (const float*)d_in[0];
    const float* x2   = (const float*)d_in[1];
    const float* xt   = (const float*)d_in[2];
    const float* gln  = (const float*)d_in[3];
    const float* bln  = (const float*)d_in[4];
    const float* w0   = (const float*)d_in[5];
    const float* b0   = (const float*)d_in[6];
    const float* wr1  = (const float*)d_in[7];
    const float* br1  = (const float*)d_in[8];
    const float* wr2  = (const float*)d_in[9];
    const float* br2  = (const float*)d_in[10];
    const float* w2   = (const float*)d_in[11];
    const float* b2   = (const float*)d_in[12];
    const float* w3   = (const float*)d_in[13];
    const float* b3   = (const float*)d_in[14];
    const float* wdec = (const float*)d_in[15];
    const float* bdec = (const float*)d_in[16];
    const float* wf   = (const float*)d_in[17];
    const float* bfv  = (const float*)d_in[18];
    float* out = (float*)d_out;

    char* ws = (char*)d_ws;
    ushort* x1c  = (ushort*)(ws + 0);
    ushort* x2c  = (ushort*)(ws + 31457280);
    ushort* X0hi = (ushort*)(ws + 62914560);
    ushort* y0hi = (ushort*)(ws + 102236160);
    ushort* t1hi = (ushort*)(ws + 110100480);
    ushort* t2hi = (ushort*)(ws + 117964800);
    ushort* decb = (ushort*)(ws + 0);
    float*  flowb = (float*)(ws + 62914560);
    char* wp = ws + 125829120;
    ushort* W0hi  = (ushort*)(wp);
    ushort* WR1hi = (ushort*)(wp + 368640);
    ushort* WR2hi = (ushort*)(wp + 442368);
    ushort* W2hi  = (ushort*)(wp + 516096);
    ushort* W3hi  = (ushort*)(wp + 589824);
    ushort* WDhi  = (ushort*)(wp + 663552);
    float*  inv1  = (float*)(wp + 786432);
    float*  inv2  = (float*)(wp + 1048576);

    pack_w_all<<<dim3(90, 6), 256, 0, stream>>>(w0, wr1, wr2, w2, w3, wdec,
        W0hi, WR1hi, WR2hi, W2hi, W3hi, WDhi);

    normpack_kernel<<<dim3(480, 3, 4), 256, 0, stream>>>(
        x1, x2, xt, gln, bln, x1c, x2c, X0hi, inv1, inv2);
    corr_mfma_kernel<<<960, 256, 0, stream>>>(x1c, x2c, inv1, inv2, X0hi);

    conv_ldsK<10><<<1920, 256, 0, stream>>>(X0hi, W0hi, b0, y0hi, nullptr, 0.f, 0, 0);
    conv_ldsK<2><<<1920, 256, 0, stream>>>(y0hi, WR1hi, br1, t1hi, nullptr, 0.1f, 1, 0);
    conv_ldsK<2><<<1920, 256, 0, stream>>>(t1hi, WR2hi, br2, t2hi, y0hi, 0.1f, 1, 1);
    conv_ldsK<2><<<1920, 256, 0, stream>>>(t2hi, W2hi, b2, t1hi, nullptr, 0.2f, 1, 0);
    conv_ldsK<2><<<1920, 256, 0, stream>>>(t1hi, W3hi, b3, t2hi, nullptr, 0.2f, 1, 0);
    deconv_fused_kernel<<<1920, 256, 0, stream>>>(t2hi, WDhi, bdec, decb);

    flow_kernel<<<1920, 256, 0, stream>>>(decb, wf, bfv, flowb);
    resize_kernel<<<7680, 256, 0, stream>>>(flowb, out);

    (void)in_sizes; (void)n_in; (void)out_size; (void)ws_size;
}

// Round 16
// 321.316 us; speedup vs baseline: 1.0830x; 1.0830x over previous
//
#include <hip/hip_runtime.h>
#include <math.h>

#define HH_ 96
#define WW_ 160
#define HW 15360          // 96*160
#define NPIX 61440        // 4*HW
#define CC 256
#define C0 320            // padded conv0 Cin
#define FF 64
#define H2 192
#define W2 320
#define OHW 61440         // 192*320
#define HO 768
#define WO 1280

typedef __attribute__((ext_vector_type(8))) short short8;
typedef __attribute__((ext_vector_type(4))) float f32x4;

__device__ __forceinline__ float bf2f(ushort u) {
    union { unsigned int i; float f; } v; v.i = ((unsigned int)u) << 16; return v.f;
}
__device__ __forceinline__ ushort f2bf(float f) {
    union { float f; unsigned int i; } v; v.f = f;
    unsigned int u = v.i;
    return (ushort)((u + 0x7FFFu + ((u >> 16) & 1u)) >> 16);
}

// ---------------- fused stats + pack (raw bf16) + LN ------------------------
__global__ __launch_bounds__(256) void normpack_kernel(
    const float* __restrict__ x1, const float* __restrict__ x2, const float* __restrict__ xt,
    const float* __restrict__ gam, const float* __restrict__ bet,
    ushort* __restrict__ x1c, ushort* __restrict__ x2c,
    ushort* __restrict__ Xhi, float* __restrict__ inv1, float* __restrict__ inv2) {
    __shared__ ushort tile[32 * 258];
    __shared__ float sred[4][32][2];
    const int t = threadIdx.x;
    const int w = t >> 6, l = t & 63;
    const int px4 = l & 7;
    const int cbase = t >> 3;
    const int pxt = blockIdx.x, which = blockIdx.y, b = blockIdx.z;
    const float* src = (which == 0 ? x1 : which == 1 ? x2 : xt);
    src += (size_t)b * CC * HW + pxt * 32;

    float s1[4] = {0.f, 0.f, 0.f, 0.f}, s2[4] = {0.f, 0.f, 0.f, 0.f};
#pragma unroll
    for (int it = 0; it < 8; ++it) {
        int c = it * 32 + cbase;
        f32x4 v4 = *(const f32x4*)(src + (size_t)c * HW + px4 * 4);
#pragma unroll
        for (int j = 0; j < 4; ++j) {
            float f = v4[j];
            s1[j] += f; s2[j] += f * f;
            tile[(px4 * 4 + j) * 258 + c] = f2bf(f);
        }
    }
#pragma unroll
    for (int j = 0; j < 4; ++j) {
        s1[j] += __shfl_xor(s1[j], 8);  s1[j] += __shfl_xor(s1[j], 16); s1[j] += __shfl_xor(s1[j], 32);
        s2[j] += __shfl_xor(s2[j], 8);  s2[j] += __shfl_xor(s2[j], 16); s2[j] += __shfl_xor(s2[j], 32);
    }
    if ((l >> 3) == 0) {
#pragma unroll
        for (int j = 0; j < 4; ++j) {
            sred[w][px4 * 4 + j][0] = s1[j];
            sred[w][px4 * 4 + j][1] = s2[j];
        }
    }
    __syncthreads();

    const int px = t >> 3, grp = t & 7;
    float S1 = sred[0][px][0] + sred[1][px][0] + sred[2][px][0] + sred[3][px][0];
    float S2 = sred[0][px][1] + sred[1][px][1] + sred[2][px][1] + sred[3][px][1];
    const int p = b * HW + pxt * 32 + px;
    const ushort* row = &tile[px * 258];
    if (which < 2) {
        float inv = 1.f / fmaxf(sqrtf(S2), 1e-12f);
        if (grp == 0) (which == 0 ? inv1 : inv2)[p] = inv;
        ushort* dst = (which == 0 ? x1c : x2c) + (size_t)p * CC + grp * 32;
#pragma unroll
        for (int k = 0; k < 4; ++k) {
            short8 o;
#pragma unroll
            for (int h = 0; h < 4; ++h) {
                unsigned int u2 = *(const unsigned int*)(row + grp * 32 + k * 8 + h * 2);
                o[h * 2]     = (short)(u2 & 0xFFFF);
                o[h * 2 + 1] = (short)(u2 >> 16);
            }
            *(short8*)(dst + k * 8) = o;
        }
    } else {
        float m = S1 * (1.f / 256.f);
        float var = fmaxf(S2 * (1.f / 256.f) - m * m, 0.f);
        float rs = rsqrtf(var + 1e-5f);
        ushort* dst = Xhi + (size_t)p * C0 + grp * 32;
#pragma unroll
        for (int k = 0; k < 4; ++k) {
            short8 o;
#pragma unroll
            for (int h = 0; h < 4; ++h) {
                unsigned int u2 = *(const unsigned int*)(row + grp * 32 + k * 8 + h * 2);
                int c = grp * 32 + k * 8 + h * 2;
                float f0 = (bf2f((ushort)(u2 & 0xFFFF)) - m) * rs * gam[c] + bet[c];
                float f1 = (bf2f((ushort)(u2 >> 16)) - m) * rs * gam[c + 1] + bet[c + 1];
                o[h * 2]     = (short)f2bf(f0);
                o[h * 2 + 1] = (short)f2bf(f1);
            }
            *(short8*)(dst + k * 8) = o;
        }
        if (grp < 4) {
            short8 z = {0, 0, 0, 0, 0, 0, 0, 0};
            *(short8*)(Xhi + (size_t)p * C0 + 256 + grp * 16) = z;
            *(short8*)(Xhi + (size_t)p * C0 + 256 + grp * 16 + 8) = z;
        }
    }
}

// ---------------------------------------------------------------- corr ------
__global__ __launch_bounds__(256) void corr_mfma_kernel(
    const ushort* __restrict__ x1c, const ushort* __restrict__ x2c,
    const float* __restrict__ inv1, const float* __restrict__ inv2,
    ushort* __restrict__ Xhi) {
    const int lane = threadIdx.x & 63;
    const int wv = threadIdx.x >> 6;
    const int sid = ((blockIdx.x & 7) * 120) + (blockIdx.x >> 3);   // 960 blocks
    const int b  = sid / 240;
    const int rem = sid % 240;
    const int uq = rem / 10, xt = rem % 10;
    const int u = uq * 4 + wv;
    const int x0 = xt * 16;
    const int jl = lane & 15;
    const int kg = lane >> 4;
    const short8 zero8 = {0, 0, 0, 0, 0, 0, 0, 0};

    short8 qf[8];
    {
        size_t qb = ((size_t)b * HW + u * WW_ + x0 + jl) * CC + kg * 8;
#pragma unroll
        for (int ks = 0; ks < 8; ++ks)
            qf[ks] = *(const short8*)(x1c + qb + ks * 32);
    }
    float iv1v[4];
#pragma unroll
    for (int r = 0; r < 4; ++r)
        iv1v[r] = inv1[b * HW + u * WW_ + x0 + kg * 4 + r];

    for (int dy = -3; dy <= 3; ++dy) {
        const int y = u + dy;
        if ((unsigned)y >= (unsigned)HH_) continue;
        const int w = u + 2 * dy;
        const bool rowok = (unsigned)w < (unsigned)HH_;

        f32x4 acc0 = (f32x4){0.f, 0.f, 0.f, 0.f};
        f32x4 acc1 = (f32x4){0.f, 0.f, 0.f, 0.f};
        if (rowok) {
#pragma unroll
            for (int nt = 0; nt < 2; ++nt) {
                int kx = x0 - 6 + jl + 16 * nt;
                bool ok = (unsigned)kx < (unsigned)WW_;
                int kxc = min(max(kx, 0), WW_ - 1);
                size_t kb = ((size_t)b * HW + w * WW_ + kxc) * CC + kg * 8;
#pragma unroll
                for (int ks = 0; ks < 8; ++ks) {
                    short8 bv = *(const short8*)(x2c + kb + ks * 32);
                    if (!ok) bv = zero8;
                    if (nt == 0)
                        acc0 = __builtin_amdgcn_mfma_f32_16x16x32_bf16(qf[ks], bv, acc0, 0, 0, 0);
                    else
                        acc1 = __builtin_amdgcn_mfma_f32_16x16x32_bf16(qf[ks], bv, acc1, 0, 0, 0);
                }
            }
        }
#pragma unroll
        for (int nt = 0; nt < 2; ++nt) {
            int j = jl + 16 * nt;
#pragma unroll
            for (int r = 0; r < 4; ++r) {
                int q = kg * 4 + r;
                int tt = j - q - 6;
                if (tt & 1) continue;
                int dx = tt >> 1;
                if (dx < -3 || dx > 3) continue;
                int cx = x0 + q + dx;
                if ((unsigned)cx >= (unsigned)WW_) continue;
                float v = 0.f;
                if (rowok) {
                    int pbx = min(max(x0 + q + 2 * dx, 0), WW_ - 1);
                    float iv2 = inv2[b * HW + w * WW_ + pbx];
                    v = (nt == 0 ? acc0[r] : acc1[r]) * iv1v[r] * iv2;
                }
                size_t o = ((size_t)(b * HW + y * WW_ + cx)) * C0
                         + 256 + (dy + 3) * 7 + (dx + 3);
                Xhi[o] = f2bf(v);
            }
        }
    }
}

// ------------------------------------------------------------ weight pack ---
__global__ void pack_w_all(const float* __restrict__ w0, const float* __restrict__ wr1,
                           const float* __restrict__ wr2, const float* __restrict__ w2,
                           const float* __restrict__ w3, const float* __restrict__ wdec,
                           ushort* __restrict__ W0, ushort* __restrict__ WR1,
                           ushort* __restrict__ WR2, ushort* __restrict__ W2o,
                           ushort* __restrict__ W3o, ushort* __restrict__ WD) {
    int job = blockIdx.y;
    const float* w = job == 0 ? w0 : job == 1 ? wr1 : job == 2 ? wr2
                   : job == 3 ? w2 : job == 4 ? w3 : wdec;
    ushort* dst = job == 0 ? W0 : job == 1 ? WR1 : job == 2 ? WR2
                : job == 3 ? W2o : job == 4 ? W3o : WD;
    int CinReal = job == 0 ? 305 : 64;
    int KC = job == 0 ? 10 : 2;
    int isDeconv = (job == 5);
    int gid = blockIdx.x * blockDim.x + threadIdx.x;
    int total = 9 * KC * 4 * 64;
    if (gid >= total) return;
    int lane = gid & 63;
    int nt = (gid >> 6) & 3;
    int kc = (gid >> 8) % KC;
    int slot = (gid >> 8) / KC;
    int co = nt * 16 + (lane & 15);
    int ky = slot / 3, kx = slot % 3;
    for (int j = 0; j < 8; ++j) {
        int ci = kc * 32 + (lane >> 4) * 8 + j;
        float v = 0.f;
        if (ci < CinReal) {
            if (isDeconv) v = w[((size_t)(ci * 64 + co) * 3 + (2 - ky)) * 3 + (2 - kx)];
            else          v = w[((size_t)(co * CinReal + ci) * 3 + ky) * 3 + kx];
        }
        dst[(size_t)gid * 8 + j] = f2bf(v);
    }
}

// ---- conv0: 512-thread block, 8 rows x 16 px tile, wave = (row-pair, coh) --
// Wave computes 2 rows x 16 px x 32 co -> per (tap,kc): 2 KB W feeds 4 MFMAs
// (0.5 KB/MFMA, halves conv0's W L2 traffic). LDS chunk: kg[4] x row[10] x
// px[18] x ch[8]; kg stride 1480 ushorts (740 dwords = 4 mod 32, the proven
// conflict-free banking of conv_lds2). 480 blocks, 3840 waves.
__global__ __launch_bounds__(512) void conv0_kernel(
    const ushort* __restrict__ Ahi,
    const ushort* __restrict__ Whi,
    const float* __restrict__ bias,
    ushort* __restrict__ Ohi) {
    constexpr int KC = 10, CIN = 320;
    __shared__ ushort lds[2 * 5920];
    const int t = threadIdx.x;
    const int lane = t & 63;
    const int wave = t >> 6;          // 0..7
    const int rp = wave >> 1;         // row-pair 0..3
    const int coh = wave & 1;         // co half
    const int kg = lane >> 4;
    const int jl = lane & 15;
    const short8 zero8 = {0, 0, 0, 0, 0, 0, 0, 0};

    const int sid = ((blockIdx.x & 7) * 60) + (blockIdx.x >> 3);   // 480 blocks
    const int b0 = sid / 120;
    const int rm = sid % 120;
    const int yo = rm / 10, xw = rm % 10;
    const int y0 = yo * 8;
    const int x0 = xw * 16;
    const size_t rowbase = (size_t)b0 * HW;

    f32x4 acc[2][2];                  // [row-in-pair][nt]
#pragma unroll
    for (int r = 0; r < 2; ++r) {
        acc[r][0] = (f32x4){0.f, 0.f, 0.f, 0.f};
        acc[r][1] = (f32x4){0.f, 0.f, 0.f, 0.f};
    }

    // stage: 10 rows x 18 px x 4 kg = 720 16B elements
    auto stage = [&](ushort* buf, int kc) {
#pragma unroll
        for (int i = 0; i < 2; ++i) {
            int e = t + i * 512;
            if (e < 720) {
                int kge = e & 3;
                int q = e >> 2;
                int pe = q % 18;
                int re = q / 18;
                int gy = y0 - 1 + re, gx = x0 - 1 + pe;
                bool ok = ((unsigned)gy < 96u) && ((unsigned)gx < 160u);
                short8 vh = zero8;
                if (ok) {
                    size_t ga = ((rowbase + gy * WW_ + gx) * (size_t)CIN) + kc * 32 + kge * 8;
                    vh = *(const short8*)(Ahi + ga);
                }
                *(short8*)(buf + kge * 1480 + (re * 18 + pe) * 8) = vh;
            }
        }
    };

    stage(lds, 0);

#pragma unroll 1
    for (int kc = 0; kc < KC; ++kc) {
        __syncthreads();
        if (kc + 1 < KC) stage(lds + ((kc + 1) & 1) * 5920, kc + 1);
        const ushort* bufc = lds + (kc & 1) * 5920;
#pragma unroll
        for (int tap = 0; tap < 9; ++tap) {
            const int dy = tap / 3 - 1, dx = tap % 3 - 1;
            const int a0i = kg * 1480 + ((rp * 2 + 0 + dy + 1) * 18 + (jl + dx + 1)) * 8;
            const int a1i = kg * 1480 + ((rp * 2 + 1 + dy + 1) * 18 + (jl + dx + 1)) * 8;
            short8 ah0 = *(const short8*)(bufc + a0i);
            short8 ah1 = *(const short8*)(bufc + a1i);
            const ushort* wt = Whi + (size_t)(tap * KC + kc) * 2048;
#pragma unroll
            for (int nt = 0; nt < 2; ++nt) {
                short8 bh = *(const short8*)(wt + (((coh << 1) | nt) * 64 + lane) * 8);
                acc[0][nt] = __builtin_amdgcn_mfma_f32_16x16x32_bf16(ah0, bh, acc[0][nt], 0, 0, 0);
                acc[1][nt] = __builtin_amdgcn_mfma_f32_16x16x32_bf16(ah1, bh, acc[1][nt], 0, 0, 0);
            }
        }
    }

#pragma unroll
    for (int rr = 0; rr < 2; ++rr) {
#pragma unroll
        for (int r = 0; r < 4; ++r) {
            size_t pr = rowbase + (y0 + rp * 2 + rr) * WW_ + x0 + kg * 4 + r;
#pragma unroll
            for (int nt = 0; nt < 2; ++nt) {
                int co = ((coh << 1) | nt) * 16 + jl;
                Ohi[pr * 64 + co] = f2bf(acc[rr][nt][r] + bias[co]);
            }
        }
    }
}

// ------ small conv core (CIN=64): 2 rows x 16 px, wave = (row, co-half) -----
__global__ __launch_bounds__(256, 8) void conv_lds2(
    const ushort* __restrict__ Ahi,
    const ushort* __restrict__ Whi,
    const float* __restrict__ bias,
    ushort* __restrict__ Ohi,
    const ushort* __restrict__ Rhi,
    float slope, int act, int hasres) {
    __shared__ ushort lds[2 * 2336];
    const int t = threadIdx.x;
    const int lane = t & 63;
    const int wave = t >> 6;
    const int row_w = wave >> 1;
    const int coh = wave & 1;
    const int kg = lane >> 4;
    const int jl = lane & 15;
    const short8 zero8 = {0, 0, 0, 0, 0, 0, 0, 0};

    const int sid = ((blockIdx.x & 7) * 240) + (blockIdx.x >> 3);   // 1920 blocks
    const int b0 = sid / 480;
    const int rm = sid % 480;
    const int yp = rm / 10, xw = rm % 10;
    const int y0 = yp * 2;
    const int x0 = xw * 16;
    const size_t rowbase = (size_t)b0 * HW;

    f32x4 acc[2];
    acc[0] = (f32x4){0.f, 0.f, 0.f, 0.f};
    acc[1] = (f32x4){0.f, 0.f, 0.f, 0.f};

    auto stage = [&](ushort* buf, int kc) {
#pragma unroll
        for (int i = 0; i < 2; ++i) {
            int e = t + i * 256;
            if (e < 288) {
                int kge = e & 3;
                int q = e >> 2;
                int pe = q % 18;
                int re = q / 18;
                int gy = y0 - 1 + re, gx = x0 - 1 + pe;
                bool ok = ((unsigned)gy < 96u) && ((unsigned)gx < 160u);
                short8 vh = zero8;
                if (ok) {
                    size_t ga = ((rowbase + gy * WW_ + gx) * 64) + kc * 32 + kge * 8;
                    vh = *(const short8*)(Ahi + ga);
                }
                *(short8*)(buf + kge * 584 + (re * 18 + pe) * 8) = vh;
            }
        }
    };

    stage(lds, 0);

#pragma unroll 1
    for (int kc = 0; kc < 2; ++kc) {
        __syncthreads();
        if (kc == 0) stage(lds + 2336, 1);
        const ushort* bufc = lds + (kc & 1) * 2336;
#pragma unroll
        for (int tap = 0; tap < 9; ++tap) {
            const int dy = tap / 3 - 1, dx = tap % 3 - 1;
            const int abase = kg * 584 + (row_w + dy + 1) * 144 + (jl + dx + 1) * 8;
            short8 ah = *(const short8*)(bufc + abase);
            const ushort* wt = Whi + (size_t)(tap * 2 + kc) * 2048;
#pragma unroll
            for (int nt = 0; nt < 2; ++nt) {
                short8 bh = *(const short8*)(wt + (((coh << 1) | nt) * 64 + lane) * 8);
                acc[nt] = __builtin_amdgcn_mfma_f32_16x16x32_bf16(ah, bh, acc[nt], 0, 0, 0);
            }
        }
    }

#pragma unroll
    for (int r = 0; r < 4; ++r) {
        size_t pr = rowbase + (y0 + row_w) * WW_ + x0 + kg * 4 + r;
#pragma unroll
        for (int nt = 0; nt < 2; ++nt) {
            int co = ((coh << 1) | nt) * 16 + jl;
            float vv = acc[nt][r] + bias[co];
            size_t oo = pr * 64 + co;
            if (hasres) vv += bf2f(Rhi[oo]);
            if (act) vv = vv >= 0.f ? vv : vv * slope;
            Ohi[oo] = f2bf(vv);
        }
    }
}

// -------- fused transposed conv (4 par), bf16 out, wave = (row, co-half) ----
__global__ __launch_bounds__(256, 6) void deconv_fused_kernel(
    const ushort* __restrict__ Ahi,
    const ushort* __restrict__ Whi,
    const float* __restrict__ bias,
    ushort* __restrict__ decb) {
    const int lane = threadIdx.x & 63;
    const int wave = threadIdx.x >> 6;
    const int row_w = wave >> 1;
    const int coh = wave & 1;
    const int kg = lane >> 4;
    const short8 zero8 = {0, 0, 0, 0, 0, 0, 0, 0};

    const int sid = ((blockIdx.x & 7) * 240) + (blockIdx.x >> 3);   // 1920 blocks
    const int b0 = sid / 480;
    const int rm = sid % 480;
    const int yp = rm / 10, xh = rm % 10;
    const int y0 = yp * 2 + row_w;
    const int x0 = xh * 16;
    const size_t rowbase = (size_t)b0 * HW;

    f32x4 acc[4][2];
#pragma unroll
    for (int p = 0; p < 4; ++p) {
        acc[p][0] = (f32x4){0.f, 0.f, 0.f, 0.f};
        acc[p][1] = (f32x4){0.f, 0.f, 0.f, 0.f};
    }

    const int nuse[4]   = {4, 2, 2, 1};
    const int upar[4][4] = {{0, 1, 2, 3}, {1, 3, -1, -1}, {2, 3, -1, -1}, {3, -1, -1, -1}};
    const int uslt[4][4] = {{4, 3, 1, 0}, {5, 2, -1, -1}, {7, 6, -1, -1}, {8, -1, -1, -1}};

#pragma unroll
    for (int o = 0; o < 4; ++o) {
        const int ody = o >> 1, odx = o & 1;
        int yy = y0 + ody, xx = x0 + (lane & 15) + odx;
        bool v = (unsigned)yy < 96u && (unsigned)xx < 160u;
        int yyc = min(yy, 95), xxc = min(xx, 159);
        size_t a = (rowbase + yyc * WW_ + xxc) * 64 + kg * 8;
#pragma unroll
        for (int kc = 0; kc < 2; ++kc) {
            short8 ah = *(const short8*)(Ahi + a + kc * 32);
            if (!v) ah = zero8;
#pragma unroll
            for (int u = 0; u < 4; ++u) {
                if (u >= nuse[o]) break;
                int par = upar[o][u], slot = uslt[o][u];
#pragma unroll
                for (int nt = 0; nt < 2; ++nt) {
                    short8 bh = *(const short8*)(Whi + ((size_t)slot * 2 + kc) * 2048
                                                 + (((coh << 1) | nt) * 64 + lane) * 8);
                    acc[par][nt] = __builtin_amdgcn_mfma_f32_16x16x32_bf16(ah, bh, acc[par][nt], 0, 0, 0);
                }
            }
        }
    }

#pragma unroll
    for (int r = 0; r < 4; ++r) {
        int x2 = x0 + kg * 4 + r;
#pragma unroll
        for (int par = 0; par < 4; ++par) {
            int py = par >> 1, px = par & 1;
            size_t po = ((size_t)b0 * H2 + 2 * y0 + py) * W2 + 2 * x2 + px;
#pragma unroll
            for (int nt = 0; nt < 2; ++nt) {
                int co = ((coh << 1) | nt) * 16 + (lane & 15);
                decb[po * 64 + co] = f2bf(acc[par][nt][r] + bias[co]);
            }
        }
    }
}

// ------------------------- flow: 2 threads per px (32 ch each) --------------
__global__ __launch_bounds__(256) void flow_kernel(const ushort* __restrict__ decb,
                                                   const float* __restrict__ wf,
                                                   const float* __restrict__ bf2v,
                                                   float* __restrict__ flow) {
    __shared__ float wsm[1152];
    for (int i = threadIdx.x; i < 1152; i += 256) wsm[i] = wf[i];
    __syncthreads();
    int fid = ((blockIdx.x & 7) * 240) + (blockIdx.x >> 3);   // 1920 blocks
    int tid = fid * 256 + threadIdx.x;
    int p = tid >> 1, half = tid & 1;
    if (p >= 4 * OHW) return;
    int b = p / OHW, rem = p % OHW, oy = rem / W2, ox = rem % W2;
    float a0 = 0.f, a1 = 0.f;
    for (int ky = 0; ky < 3; ++ky) {
        int yy = oy + ky - 1;
        if ((unsigned)yy >= (unsigned)H2) continue;
        for (int kx = 0; kx < 3; ++kx) {
            int xx = ox + kx - 1;
            if ((unsigned)xx >= (unsigned)W2) continue;
            size_t base = ((size_t)b * OHW + yy * W2 + xx) * 64;
            int tap = ky * 3 + kx;
#pragma unroll
            for (int c8 = 0; c8 < 4; ++c8) {
                int cg = half * 4 + c8;
                short8 v8 = *(const short8*)(decb + base + cg * 8);
#pragma unroll
                for (int j = 0; j < 8; ++j) {
                    float f = bf2f((ushort)v8[j]);
                    int ci = cg * 8 + j;
                    a0 += f * wsm[ci * 9 + tap];
                    a1 += f * wsm[(64 + ci) * 9 + tap];
                }
            }
        }
    }
    a0 += __shfl_xor(a0, 1);
    a1 += __shfl_xor(a1, 1);
    if (half == 0) {
        flow[(size_t)(b * 2 + 0) * OHW + rem] = a0 + bf2v[0];
        flow[(size_t)(b * 2 + 1) * OHW + rem] = a1 + bf2v[1];
    }
}

// --------------------------------------------- resize: float4-wide outputs --
__global__ __launch_bounds__(256) void resize_kernel(const float* __restrict__ flow,
                                                     float* __restrict__ out) {
    int idx = blockIdx.x * blockDim.x + threadIdx.x;
    int total = 4 * 2 * HO * (WO / 4);
    if (idx >= total) return;
    int qx = idx % (WO / 4);
    int oy = (idx / (WO / 4)) % HO;
    int c  = (idx / ((WO / 4) * HO)) % 2;
    int b  = idx / ((WO / 4) * HO * 2);

    float sy = (oy + 0.5f) * 0.25f - 0.5f;
    int y0 = (int)floorf(sy);
    float fy = sy - y0;
    int y0c = min(max(y0, 0), H2 - 1);
    int y1c = min(max(y0 + 1, 0), H2 - 1);
    const float* r0 = flow + ((size_t)(b * 2 + c) * H2 + y0c) * W2;
    const float* r1 = flow + ((size_t)(b * 2 + c) * H2 + y1c) * W2;
    int xm = max(qx - 1, 0), xp = min(qx + 1, W2 - 1);
    float fm = (1.f - fy) * r0[xm] + fy * r1[xm];
    float f0 = (1.f - fy) * r0[qx] + fy * r1[qx];
    float fp = (1.f - fy) * r0[xp] + fy * r1[xp];
    f32x4 o;
    o[0] = (0.375f * fm + 0.625f * f0) * 4.0f;
    o[1] = (0.125f * fm + 0.875f * f0) * 4.0f;
    o[2] = (0.875f * f0 + 0.125f * fp) * 4.0f;
    o[3] = (0.625f * f0 + 0.375f * fp) * 4.0f;
    *(f32x4*)(out + (((size_t)(b * 2 + c) * HO + oy) * WO) + qx * 4) = o;
}

// =================================================================== host ===
extern "C" void kernel_launch(void* const* d_in, const int* in_sizes, int n_in,
                              void* d_out, int out_size, void* d_ws, size_t ws_size,
                              hipStream_t stream) {
    const float* x1   = (const float*)d_in[0];
    const float* x2   = (const float*)d_in[1];
    const float* xt   = (const float*)d_in[2];
    const float* gln  = (const float*)d_in[3];
    const float* bln  = (const float*)d_in[4];
    const float* w0   = (const float*)d_in[5];
    const float* b0   = (const float*)d_in[6];
    const float* wr1  = (const float*)d_in[7];
    const float* br1  = (const float*)d_in[8];
    const float* wr2  = (const float*)d_in[9];
    const float* br2  = (const float*)d_in[10];
    const float* w2   = (const float*)d_in[11];
    const float* b2   = (const float*)d_in[12];
    const float* w3   = (const float*)d_in[13];
    const float* b3   = (const float*)d_in[14];
    const float* wdec = (const float*)d_in[15];
    const float* bdec = (const float*)d_in[16];
    const float* wf   = (const float*)d_in[17];
    const float* bfv  = (const float*)d_in[18];
    float* out = (float*)d_out;

    char* ws = (char*)d_ws;
    ushort* x1c  = (ushort*)(ws + 0);
    ushort* x2c  = (ushort*)(ws + 31457280);
    ushort* X0hi = (ushort*)(ws + 62914560);
    ushort* y0hi = (ushort*)(ws + 102236160);
    ushort* t1hi = (ushort*)(ws + 110100480);
    ushort* t2hi = (ushort*)(ws + 117964800);
    ushort* decb = (ushort*)(ws + 0);
    float*  flowb = (float*)(ws + 62914560);
    char* wp = ws + 125829120;
    ushort* W0hi  = (ushort*)(wp);
    ushort* WR1hi = (ushort*)(wp + 368640);
    ushort* WR2hi = (ushort*)(wp + 442368);
    ushort* W2hi  = (ushort*)(wp + 516096);
    ushort* W3hi  = (ushort*)(wp + 589824);
    ushort* WDhi  = (ushort*)(wp + 663552);
    float*  inv1  = (float*)(wp + 786432);
    float*  inv2  = (float*)(wp + 1048576);

    pack_w_all<<<dim3(90, 6), 256, 0, stream>>>(w0, wr1, wr2, w2, w3, wdec,
        W0hi, WR1hi, WR2hi, W2hi, W3hi, WDhi);

    normpack_kernel<<<dim3(480, 3, 4), 256, 0, stream>>>(
        x1, x2, xt, gln, bln, x1c, x2c, X0hi, inv1, inv2);
    corr_mfma_kernel<<<960, 256, 0, stream>>>(x1c, x2c, inv1, inv2, X0hi);

    conv0_kernel<<<480, 512, 0, stream>>>(X0hi, W0hi, b0, y0hi);
    conv_lds2<<<1920, 256, 0, stream>>>(y0hi, WR1hi, br1, t1hi, nullptr, 0.1f, 1, 0);
    conv_lds2<<<1920, 256, 0, stream>>>(t1hi, WR2hi, br2, t2hi, y0hi, 0.1f, 1, 1);
    conv_lds2<<<1920, 256, 0, stream>>>(t2hi, W2hi, b2, t1hi, nullptr, 0.2f, 1, 0);
    conv_lds2<<<1920, 256, 0, stream>>>(t1hi, W3hi, b3, t2hi, nullptr, 0.2f, 1, 0);
    deconv_fused_kernel<<<1920, 256, 0, stream>>>(t2hi, WDhi, bdec, decb);

    flow_kernel<<<1920, 256, 0, stream>>>(decb, wf, bfv, flowb);
    resize_kernel<<<7680, 256, 0, stream>>>(flowb, out);

    (void)in_sizes; (void)n_in; (void)out_size; (void)ws_size;
}